// Round 14
// baseline (167.212 us; speedup 1.0000x reference)
//
#include <hip/hip_runtime.h>
#include <cstdint>

#define N_NODES 50000
#define N_EDGES 800000
#define F_IN    128
#define N_HEADS 4
#define HEAD_DIM 32
#define F_OUT   128

#define NBUCK   391                 // ceil(50000/128) coarse buckets (to>>7)
#define NPB     128                 // nodes per bucket
#define KA_GRID 512                 // binning blocks
#define EPB     1563                // ceil(800000/512) edges per binning block
#define CAPA    24                  // slots per (bucket, block); mean 4.0, P(>24) ~ 3e-7 total
#define REC_CAP 2560                // rec_from region per bucket; mean 2048, ~11 sigma
#define STAGE_CAP REC_CAP
#define NSTRIP  (N_NODES / 16)      // 3125 (exact)
#define NGEMM   ((NSTRIP + 7) / 8)  // 391 gemm blocks (8 waves = 8 strips = 128 rows)
// WS budget: ~38.9 MB carve (ws is ~268 MB per R13 fill counters, but stay lean).

typedef unsigned int uint32;
typedef unsigned short ushort;
typedef __attribute__((ext_vector_type(8))) short short8v;   // 8 bf16 in 4 VGPRs
typedef __attribute__((ext_vector_type(4))) float float4v;

typedef __attribute__((address_space(1))) const ushort gushort;
typedef __attribute__((address_space(3))) ushort lushort;

__device__ __forceinline__ ushort f2bf(float f) {
    uint32 u = __float_as_uint(f);
    return (ushort)((u + 0x7FFFu + ((u >> 16) & 1u)) >> 16);   // RNE
}

// alpha slot permutation: head h -> slot {0->0, 1->2, 2->1, 3->3}
// so agg half-wave g reads (head g, head g+2) as one float2 at slot 2g.

// ---------------------------------------------------------------------------
// block-wide exclusive scan over 256 ints (4 waves) — used by k_build only
// ---------------------------------------------------------------------------
__device__ __forceinline__ int block_scan_excl_256(int v, int* p_total)
{
    const int t = threadIdx.x, lane = t & 63, wv = t >> 6;
    int incl = v;
#pragma unroll
    for (int d = 1; d < 64; d <<= 1) {
        int u = __shfl_up(incl, d);
        if (lane >= d) incl += u;
    }
    __shared__ int wsum[4];
    if (lane == 63) wsum[wv] = incl;
    __syncthreads();
    int woff = 0;
#pragma unroll
    for (int j = 0; j < 4; ++j) {
        int s = wsum[j];
        if (j < wv) woff += s;
    }
    if (p_total) *p_total = wsum[0] + wsum[1] + wsum[2] + wsum[3];
    __syncthreads();
    return woff + incl - v;
}

// ---------------------------------------------------------------------------
// k_prep: split W into bf16 hi/lo in MFMA B-fragment-sequential order:
// tile (nt,kt) = 64 lanes x 16 B; lane l=(q=l>>4,c15=l&15), elem j:
// W[k = kt*32+q*8+j][n = nt*16+c15]. WTF: [tile*512 + l*8 + j] hi; +16384 lo.
// ---------------------------------------------------------------------------
__global__ __launch_bounds__(256) void k_prep(const float* __restrict__ W,
    ushort* __restrict__ WTF)
{
    const int id = blockIdx.x * 256 + threadIdx.x;
    if (id >= 32 * 64) return;
    const int tile = id >> 6, l = id & 63;
    const int q = l >> 4, c15 = l & 15;
    const int nt = tile >> 2, kt = tile & 3;
    short8v hv, lv;
#pragma unroll
    for (int j = 0; j < 8; ++j) {
        const int k = kt * 32 + q * 8 + j;
        const float w = W[k * F_OUT + nt * 16 + c15];
        const ushort hi = f2bf(w);
        const float hif = __uint_as_float((uint32)hi << 16);
        hv[j] = (short)hi;
        lv[j] = (short)f2bf(w - hif);
    }
    *(short8v*)&WTF[tile * 512 + l * 8]         = hv;
    *(short8v*)&WTF[16384 + tile * 512 + l * 8] = lv;
}

// ---------------------------------------------------------------------------
// MERGED kernel, 512-thread blocks (R13 lesson: 64-KB static LDS capped both
// paths at 8 waves/CU; 8-wave blocks give 16 waves/CU at the same 2 blocks/CU).
// Blocks [0,NGEMM) = GEMM (long poles first); [NGEMM, NGEMM+KA_GRID) = bin.
//
// bin: 512 blocks x 1563 edges, packed 4-B records (from | to_local<<16),
// per-block private priv cells (single-writer). cur[] aliases lds_buf.
//
// gemm: 8 waves x 1 strip (16 rows). All 64 KB of WTF staged via 64 x
// global_load_lds width=16 (uniform base + lane*16); B-frags then
// conflict-free ds_read_b128. Split-bf16 MFMA: hi*hi+lo*hi+hi*lo ≈ fp32.
// hbq word layout (64 dwords/row): word w = pack(bf16 dim w, bf16 dim w+64).
// ---------------------------------------------------------------------------
__global__ __launch_bounds__(512, 4) void k_bin_gemm(
    const int* __restrict__ ei, const float* __restrict__ x,
    const ushort* __restrict__ WTF,
    const float* __restrict__ attl, const float* __restrict__ attr,
    uint32* __restrict__ priv, int* __restrict__ cnts,
    uint32* __restrict__ hbq, float* __restrict__ aLp, float* __restrict__ aRp)
{
    __shared__ __attribute__((aligned(16))) char lds_buf[65536];

    if (blockIdx.x >= NGEMM) {
        // ---------------- bin path ----------------
        int* cur = (int*)lds_buf;
        const int sb = blockIdx.x - NGEMM, t = threadIdx.x;
        for (int bb = t; bb < NBUCK; bb += 512) cur[bb] = 0;
        __syncthreads();
        const int e0 = sb * EPB;
        const int lim = min(EPB, N_EDGES - e0);
        for (int i = t; i < lim; i += 512) {
            const int from = ei[e0 + i];
            const int to   = ei[N_EDGES + e0 + i];
            const int b = to >> 7;
            const int slot = atomicAdd(&cur[b], 1);
            if (slot < CAPA)                      // P ~ 3e-7 total, never fires
                priv[((size_t)b * KA_GRID + sb) * CAPA + slot] =
                    (uint32)from | ((uint32)(to & 127) << 16);
        }
        __syncthreads();
        for (int bb = t; bb < NBUCK; bb += 512)   // coalesced, single-writer
            cnts[sb * NBUCK + bb] = min(cur[bb], CAPA);
        return;
    }

    // ---------------- gemm path ----------------
    const int bid   = blockIdx.x;
    const int lane  = threadIdx.x & 63;
    const int wv    = threadIdx.x >> 6;          // 0..7
    const int q     = lane >> 4;
    const int c15   = lane & 15;

    // cooperative WTF staging: 64 x 1 KB chunks, 8 per wave (ALL waves,
    // before any strip-validity exit — barrier safety)
    ushort* wt = (ushort*)lds_buf;
#pragma unroll
    for (int i = 0; i < 8; ++i) {
        const int chunk = wv * 8 + i;
        __builtin_amdgcn_global_load_lds(
            (gushort*)(WTF + chunk * 512 + lane * 8),
            (lushort*)(wt + chunk * 512), 16, 0, 0);
    }
    __syncthreads();

    const int strip = bid * 8 + wv;
    if (strip >= NSTRIP) return;                  // wave-uniform exit
    const int row0 = strip * 16;

    // A fragments: x rows, split into bf16 hi + lo (full 128-B line coverage)
    const float* xrow = x + (size_t)(row0 + c15) * F_IN + q * 8;
    short8v ahi[4], alo[4];
#pragma unroll
    for (int kt = 0; kt < 4; ++kt) {
        const float4 f0 = *(const float4*)(xrow + kt * 32);
        const float4 f1 = *(const float4*)(xrow + kt * 32 + 4);
        const float fs[8] = {f0.x, f0.y, f0.z, f0.w, f1.x, f1.y, f1.z, f1.w};
#pragma unroll
        for (int j = 0; j < 8; ++j) {
            const ushort hi = f2bf(fs[j]);
            const float hif = __uint_as_float((uint32)hi << 16);
            ahi[kt][j] = (short)hi;
            alo[kt][j] = (short)f2bf(fs[j] - hif);
        }
    }

    float4v acc[8];
#pragma unroll
    for (int nt = 0; nt < 8; ++nt) {
        float4v a = {0.f, 0.f, 0.f, 0.f};
#pragma unroll
        for (int kt = 0; kt < 4; ++kt) {
            const short8v bh = *(const short8v*)(wt + (nt * 4 + kt) * 512 + lane * 8);
            const short8v bl = *(const short8v*)(wt + 16384 + (nt * 4 + kt) * 512 + lane * 8);
            a = __builtin_amdgcn_mfma_f32_16x16x32_bf16(ahi[kt], bh, a, 0, 0, 0);
            a = __builtin_amdgcn_mfma_f32_16x16x32_bf16(alo[kt], bh, a, 0, 0, 0);
            a = __builtin_amdgcn_mfma_f32_16x16x32_bf16(ahi[kt], bl, a, 0, 0, 0);
        }
        acc[nt] = a;
    }

    // packed h store: word nt*16+c15 = pack(dim w, dim w+64)
#pragma unroll
    for (int nt = 0; nt < 4; ++nt) {
#pragma unroll
        for (int r = 0; r < 4; ++r) {
            const uint32 d = (uint32)f2bf(acc[nt][r]) | ((uint32)f2bf(acc[nt + 4][r]) << 16);
            hbq[(size_t)(row0 + q * 4 + r) * 64 + nt * 16 + c15] = d;
        }
    }

    // alphas from exact fp32 accumulators (permuted slot store)
    float aLacc[4][4] = {{0.f}}, aRacc[4][4] = {{0.f}};
#pragma unroll
    for (int nt = 0; nt < 8; ++nt) {
        const float alv = attl[nt * 16 + c15];
        const float arv = attr[nt * 16 + c15];
        const int hh = nt >> 1;
#pragma unroll
        for (int r = 0; r < 4; ++r) {
            aLacc[r][hh] = fmaf(acc[nt][r], alv, aLacc[r][hh]);
            aRacc[r][hh] = fmaf(acc[nt][r], arv, aRacc[r][hh]);
        }
    }
#pragma unroll
    for (int r = 0; r < 4; ++r) {
#pragma unroll
        for (int hh = 0; hh < 4; ++hh) {
            float vl = aLacc[r][hh], vr = aRacc[r][hh];
#pragma unroll
            for (int d = 1; d < 16; d <<= 1) {
                vl += __shfl_xor(vl, d);
                vr += __shfl_xor(vr, d);
            }
            if (c15 == hh) {
                const int row = row0 + q * 4 + r;
                const int pos = (hh & 1) * 2 + (hh >> 1);   // permuted slot
                aLp[row * N_HEADS + pos] = vl;
                aRp[row * N_HEADS + pos] = vr;
            }
        }
    }
}

// ---------------------------------------------------------------------------
// k_build: one block per bucket (391 blocks, 128 nodes each). Fixed CSR
// region rec_from[b*REC_CAP ...]. Per-thread 2 sub-counts -> block scan of
// 512; coalesced sweep of the bucket's packed records (48 KB) -> LDS stage;
// LDS histogram + scan -> count/offsets; scatter confined to own region.
// ---------------------------------------------------------------------------
__global__ __launch_bounds__(256) void k_build(const uint32* __restrict__ priv,
    const int* __restrict__ cnts,
    int* __restrict__ count, int* __restrict__ offsets, int* __restrict__ rec_from)
{
    __shared__ uint32 stage[STAGE_CAP];           // 10 KB
    __shared__ int so_s[KA_GRID];                 // 2 KB
    __shared__ ushort cts_s[KA_GRID];             // 1 KB
    __shared__ int hist[NPB], curn[NPB];
    const int b = blockIdx.x, t = threadIdx.x;

    int c[2], s = 0;
#pragma unroll
    for (int j = 0; j < 2; ++j) {
        c[j] = cnts[(size_t)(2 * t + j) * NBUCK + b];
        s += c[j];
    }
    int total;
    int ex = block_scan_excl_256(s, &total);
#pragma unroll
    for (int j = 0; j < 2; ++j) {
        so_s[2 * t + j]  = ex;
        cts_s[2 * t + j] = (ushort)c[j];
        ex += c[j];
    }
    if (t < NPB) hist[t] = 0;
    __syncthreads();

    const uint32* pbase = priv + (size_t)b * KA_GRID * CAPA;
    for (int idx = t; idx < KA_GRID * CAPA; idx += 256) {   // 48 iters, coalesced
        const int sb = idx / CAPA;                // magic-mul division
        const int sl = idx - sb * CAPA;
        if (sl < (int)cts_s[sb]) {
            const int p = so_s[sb] + sl;
            if (p < STAGE_CAP) stage[p] = pbase[idx];
        }
    }
    __syncthreads();

    const int S = min(total, STAGE_CAP);
    for (int i = t; i < S; i += 256) atomicAdd(&hist[stage[i] >> 16], 1);
    __syncthreads();

    const int hv = (t < NPB) ? hist[t] : 0;
    int tot2;
    const int lo = block_scan_excl_256(hv, &tot2);
    const int rbase = b * REC_CAP;
    const int n = b * NPB + t;
    if (t < NPB && n < N_NODES) {
        count[n]   = hv;
        offsets[n] = rbase + lo;
    }
    if (t < NPB) curn[t] = lo;
    __syncthreads();

    for (int i = t; i < S; i += 256) {
        const uint32 e = stage[i];
        const int pos = atomicAdd(&curn[e >> 16], 1);
        rec_from[rbase + pos] = (int)(e & 0xFFFFu);
    }
}

// ---------------------------------------------------------------------------
// k_agg: pull aggregation. Wave per node; lane l owns dims (l, l+64) via hbq
// word l — heads = permuted alpha slots (hsel, hsel+1).
// Edge records (f, e0, e1) broadcast via ONE ds_read_b128 per edge (replaces
// 3 bpermutes — DS ops are in-order per wave, same-address reads broadcast).
// Softmax max-shift cancels in ex/sum(ex); att <= ~10 so no fp32 overflow.
// ---------------------------------------------------------------------------
__global__ __launch_bounds__(256) void k_agg(const int* __restrict__ rec_from,
    const int* __restrict__ count, const int* __restrict__ offsets,
    const float* __restrict__ aLp, const float* __restrict__ aRp,
    const uint32* __restrict__ hbq,
    const float* __restrict__ bias, float* __restrict__ out)
{
    __shared__ float4 ebuf[4][2][32];             // 4 KB: [wave][half][slot]
    const int lane = threadIdx.x & 63;
    const int wvb  = threadIdx.x >> 6;
    const int n = blockIdx.x * 4 + wvb;
    if (n >= N_NODES) return;
    const int cnt  = count[n];
    const int off  = offsets[n];
    const int hb   = lane >> 5;         // half-wave
    const int hsel = hb * 2;            // permuted slot pair
    const int l31  = lane & 31;
    const float2 arv = *(const float2*)&aRp[n * N_HEADS + hsel];
    float ax = 0.f, ay = 0.f, ds0 = 0.f, ds1 = 0.f;

    for (int base = 0; base < cnt; base += 32) {
        const int m = min(32, cnt - base);
        if (l31 < m) {
            const int vf = rec_from[off + base + l31];        // coalesced
            const float2 af = *(const float2*)&aLp[vf * N_HEADS + hsel];
            float t0 = af.x + arv.x; t0 = (t0 > 0.f) ? t0 : 0.2f * t0;
            float t1 = af.y + arv.y; t1 = (t1 > 0.f) ? t1 : 0.2f * t1;
            ebuf[wvb][hb][l31] = make_float4(__int_as_float(vf),
                                             __expf(t0), __expf(t1), 0.f);
        }
        __asm volatile("s_waitcnt lgkmcnt(0)" ::: "memory");  // writes visible
        int i = 0;
        for (; i + 8 <= m; i += 8) {
            float4 r[8]; uint32 h[8];
#pragma unroll
            for (int j = 0; j < 8; ++j) r[j] = ebuf[wvb][hb][i + j];
#pragma unroll
            for (int j = 0; j < 8; ++j)
                h[j] = hbq[(size_t)__float_as_int(r[j].x) * 64 + lane];
#pragma unroll
            for (int j = 0; j < 8; ++j) {
                ax = fmaf(r[j].y, __uint_as_float(h[j] << 16), ax);
                ay = fmaf(r[j].z, __uint_as_float(h[j] & 0xFFFF0000u), ay);
                ds0 += r[j].y; ds1 += r[j].z;
            }
        }
        for (; i + 4 <= m; i += 4) {
            float4 r[4]; uint32 h[4];
#pragma unroll
            for (int j = 0; j < 4; ++j) r[j] = ebuf[wvb][hb][i + j];
#pragma unroll
            for (int j = 0; j < 4; ++j)
                h[j] = hbq[(size_t)__float_as_int(r[j].x) * 64 + lane];
#pragma unroll
            for (int j = 0; j < 4; ++j) {
                ax = fmaf(r[j].y, __uint_as_float(h[j] << 16), ax);
                ay = fmaf(r[j].z, __uint_as_float(h[j] & 0xFFFF0000u), ay);
                ds0 += r[j].y; ds1 += r[j].z;
            }
        }
        for (; i < m; ++i) {
            const float4 r = ebuf[wvb][hb][i];
            const uint32 hv = hbq[(size_t)__float_as_int(r.x) * 64 + lane];
            ax = fmaf(r.y, __uint_as_float(hv << 16), ax);
            ay = fmaf(r.z, __uint_as_float(hv & 0xFFFF0000u), ay);
            ds0 += r.y; ds1 += r.z;
        }
    }
    const float inv0 = 1.0f / (ds0 + 1e-9f);
    const float inv1 = 1.0f / (ds1 + 1e-9f);
    out[n * F_OUT + lane]      = ax * inv0 + bias[lane];
    out[n * F_OUT + 64 + lane] = ay * inv1 + bias[64 + lane];
}

// ---------------------------------------------------------------------------
extern "C" void kernel_launch(void* const* d_in, const int* in_sizes, int n_in,
                              void* d_out, int out_size, void* d_ws, size_t ws_size,
                              hipStream_t stream)
{
    const float* x    = (const float*)d_in[0];
    const int*   ei   = (const int*)d_in[1];
    const float* W    = (const float*)d_in[2];
    const float* attl = (const float*)d_in[3];
    const float* attr = (const float*)d_in[4];
    const float* bias = (const float*)d_in[5];
    float* out = (float*)d_out;

    char* p = (char*)d_ws;
    auto carve = [&](size_t bytes) -> char* {
        char* q = p;
        p += (bytes + 255) & ~size_t(255);
        return q;
    };
    uint32* hbq      = (uint32*)carve((size_t)N_NODES * 64 * 4);           // 12.8 MB
    uint32* priv     = (uint32*)carve((size_t)NBUCK * KA_GRID * CAPA * 4); // 19.2 MB
    int*    rec_from = (int*)carve((size_t)NBUCK * REC_CAP * 4);           // 4.0 MB
    ushort* WTF      = (ushort*)carve(32768 * 2);                          // 64 KB
    float*  aLp      = (float*)carve((size_t)N_NODES * N_HEADS * 4);
    float*  aRp      = (float*)carve((size_t)N_NODES * N_HEADS * 4);
    int*    cnts     = (int*)carve((size_t)KA_GRID * NBUCK * 4);           // 0.8 MB
    int*    count    = (int*)carve((size_t)N_NODES * 4);
    int*    offsets  = (int*)carve((size_t)N_NODES * 4);

    k_prep<<<8, 256, 0, stream>>>(W, WTF);
    k_bin_gemm<<<NGEMM + KA_GRID, 512, 0, stream>>>(ei, x, WTF,
                                                    attl, attr, priv, cnts,
                                                    hbq, aLp, aRp);
    k_build<<<NBUCK, 256, 0, stream>>>(priv, cnts, count, offsets, rec_from);
    k_agg<<<(N_NODES + 3) / 4, 256, 0, stream>>>(rec_from, count, offsets,
                                                 aLp, aRp, hbq, bias, out);
}

// Round 15
// 154.018 us; speedup vs baseline: 1.0857x; 1.0857x over previous
//
#include <hip/hip_runtime.h>
#include <cstdint>

#define N_NODES 50000
#define N_EDGES 800000
#define F_IN    128
#define N_HEADS 4
#define HEAD_DIM 32
#define F_OUT   128

#define NBUCK   391                 // ceil(50000/128) coarse buckets (to>>7)
#define NPB     128                 // nodes per bucket
#define KA_GRID 512                 // binning blocks
#define EPB     1563                // ceil(800000/512) edges per binning block
#define EPB_PAD 1568                // blockarr stride (16-B aligned)
#define REC_CAP 2560                // rec_from region per bucket; mean 2048, ~11 sigma
#define STAGE_CAP REC_CAP
#define NSTRIP  (N_NODES / 16)      // 3125 (exact)
#define NGEMM   ((NSTRIP + 3) / 4)  // 782 gemm blocks (4 waves = 4 strips = 64 rows)
// WS total ~23.7 MB.

typedef unsigned int uint32;
typedef unsigned short ushort;
typedef __attribute__((ext_vector_type(8))) short short8v;   // 8 bf16 in 4 VGPRs
typedef __attribute__((ext_vector_type(4))) float float4v;

typedef __attribute__((address_space(1))) const ushort gushort;
typedef __attribute__((address_space(3))) ushort lushort;

__device__ __forceinline__ ushort f2bf(float f) {
    uint32 u = __float_as_uint(f);
    return (ushort)((u + 0x7FFFu + ((u >> 16) & 1u)) >> 16);   // RNE
}

// alpha slot permutation: head h -> slot {0->0, 1->2, 2->1, 3->3}
// so agg half-wave g reads (head g, head g+2) as one float2 at slot 2g.

// ---------------------------------------------------------------------------
// block-wide exclusive scan over 256 ints (4 waves)
// ---------------------------------------------------------------------------
__device__ __forceinline__ int block_scan_excl_256(int v, int* p_total)
{
    const int t = threadIdx.x, lane = t & 63, wv = t >> 6;
    int incl = v;
#pragma unroll
    for (int d = 1; d < 64; d <<= 1) {
        int u = __shfl_up(incl, d);
        if (lane >= d) incl += u;
    }
    __shared__ int wsum[4];
    if (lane == 63) wsum[wv] = incl;
    __syncthreads();
    int woff = 0;
#pragma unroll
    for (int j = 0; j < 4; ++j) {
        int s = wsum[j];
        if (j < wv) woff += s;
    }
    if (p_total) *p_total = wsum[0] + wsum[1] + wsum[2] + wsum[3];
    __syncthreads();
    return woff + incl - v;
}

// ---------------------------------------------------------------------------
// k_prep: split W into bf16 hi/lo in MFMA B-fragment-sequential order:
// tile (nt,kt) = 64 lanes x 16 B; lane l=(q=l>>4,c15=l&15), elem j:
// W[k = kt*32+q*8+j][n = nt*16+c15]. WTF: [tile*512 + l*8 + j] hi; +16384 lo.
// ---------------------------------------------------------------------------
__global__ __launch_bounds__(256) void k_prep(const float* __restrict__ W,
    ushort* __restrict__ WTF)
{
    const int id = blockIdx.x * 256 + threadIdx.x;
    if (id >= 32 * 64) return;
    const int tile = id >> 6, l = id & 63;
    const int q = l >> 4, c15 = l & 15;
    const int nt = tile >> 2, kt = tile & 3;
    short8v hv, lv;
#pragma unroll
    for (int j = 0; j < 8; ++j) {
        const int k = kt * 32 + q * 8 + j;
        const float w = W[k * F_OUT + nt * 16 + c15];
        const ushort hi = f2bf(w);
        const float hif = __uint_as_float((uint32)hi << 16);
        hv[j] = (short)hi;
        lv[j] = (short)f2bf(w - hif);
    }
    *(short8v*)&WTF[tile * 512 + l * 8]         = hv;
    *(short8v*)&WTF[16384 + tile * 512 + l * 8] = lv;
}

// ---------------------------------------------------------------------------
// MERGED kernel (R13 config): blocks [0,KA_GRID) bin; rest GEMM.
//
// bin (R14 post-mortem: priv's 19.2-MB sparse footprint = ~20 MB of dirty
// lines + a 19.2-MB build sweep, for 3.2 MB of payload): counting-sort the
// block's 1563 edges IN LDS (count -> pair-scan -> scatter), flush ONE dense
// coalesced array blockarr[sb] (6.3 KB), plus b-major run directory
// cnts[b][sb] / offs[b][sb]. Bin writes: 19.2+0.8 -> 4.8 MB total.
//
// gemm: one wave per 16-row strip, 4 strips/block. All 64 KB of WTF staged
// via 64 x global_load_lds width=16 (uniform base + lane*16); B-frags then
// conflict-free ds_read_b128. Split-bf16 MFMA: hi*hi+lo*hi+hi*lo ≈ fp32.
// hbq word layout (64 dwords/row): word w = pack(bf16 dim w, bf16 dim w+64).
// ---------------------------------------------------------------------------
__global__ __launch_bounds__(256, 2) void k_bin_gemm(
    const int* __restrict__ ei, const float* __restrict__ x,
    const ushort* __restrict__ WTF,
    const float* __restrict__ attl, const float* __restrict__ attr,
    uint32* __restrict__ blockarr, int* __restrict__ cnts, int* __restrict__ offs,
    uint32* __restrict__ hbq, float* __restrict__ aLp, float* __restrict__ aRp)
{
    __shared__ __attribute__((aligned(16))) char lds_buf[65536];

    if (blockIdx.x < KA_GRID) {
        // ---------------- bin path: local counting sort ----------------
        int*    cur = (int*)lds_buf;              // [512] (NBUCK padded)
        int*    off = cur + 512;                  // [512]
        uint32* stg = (uint32*)(off + 512);       // [EPB]
        const int sb = blockIdx.x, t = threadIdx.x;

        cur[t] = 0; cur[t + 256] = 0;
        __syncthreads();

        const int e0 = sb * EPB;
        const int lim = min(EPB, N_EDGES - e0);
        for (int i = t; i < lim; i += 256)        // pass 1: bucket histogram
            atomicAdd(&cur[ei[N_EDGES + e0 + i] >> 7], 1);
        __syncthreads();

        const int c0 = cur[2 * t], c1 = cur[2 * t + 1];
        const int ex = block_scan_excl_256(c0 + c1, nullptr);
        off[2 * t]     = ex;
        off[2 * t + 1] = ex + c0;
        __syncthreads();

        for (int bb = t; bb < NBUCK; bb += 256) { // run directory (b-major)
            cnts[(size_t)bb * KA_GRID + sb] = cur[bb];
            offs[(size_t)bb * KA_GRID + sb] = off[bb];
        }
        __syncthreads();                          // directory read before cursor mutation

        for (int i = t; i < lim; i += 256) {      // pass 2: scatter into LDS
            const int from = ei[e0 + i];
            const int to   = ei[N_EDGES + e0 + i];
            const int pos = atomicAdd(&off[to >> 7], 1);
            stg[pos] = (uint32)from | ((uint32)(to & 127) << 16);
        }
        __syncthreads();

        uint32* dst = blockarr + (size_t)sb * EPB_PAD;
        for (int i = t; i < lim; i += 256)        // dense coalesced flush
            dst[i] = stg[i];
        return;
    }

    // ---------------- gemm path (R13 verbatim) ----------------
    const int bid   = blockIdx.x - KA_GRID;
    const int lane  = threadIdx.x & 63;
    const int wv    = threadIdx.x >> 6;
    const int q     = lane >> 4;
    const int c15   = lane & 15;

    ushort* wt = (ushort*)lds_buf;
#pragma unroll
    for (int i = 0; i < 16; ++i) {
        const int chunk = wv * 16 + i;
        __builtin_amdgcn_global_load_lds(
            (gushort*)(WTF + chunk * 512 + lane * 8),
            (lushort*)(wt + chunk * 512), 16, 0, 0);
    }
    __syncthreads();

    const int strip = bid * 4 + wv;
    if (strip >= NSTRIP) return;                  // wave-uniform exit
    const int row0 = strip * 16;

    const float* xrow = x + (size_t)(row0 + c15) * F_IN + q * 8;
    short8v ahi[4], alo[4];
#pragma unroll
    for (int kt = 0; kt < 4; ++kt) {
        const float4 f0 = *(const float4*)(xrow + kt * 32);
        const float4 f1 = *(const float4*)(xrow + kt * 32 + 4);
        const float fs[8] = {f0.x, f0.y, f0.z, f0.w, f1.x, f1.y, f1.z, f1.w};
#pragma unroll
        for (int j = 0; j < 8; ++j) {
            const ushort hi = f2bf(fs[j]);
            const float hif = __uint_as_float((uint32)hi << 16);
            ahi[kt][j] = (short)hi;
            alo[kt][j] = (short)f2bf(fs[j] - hif);
        }
    }

    float4v acc[8];
#pragma unroll
    for (int nt = 0; nt < 8; ++nt) {
        float4v a = {0.f, 0.f, 0.f, 0.f};
#pragma unroll
        for (int kt = 0; kt < 4; ++kt) {
            const short8v bh = *(const short8v*)(wt + (nt * 4 + kt) * 512 + lane * 8);
            const short8v bl = *(const short8v*)(wt + 16384 + (nt * 4 + kt) * 512 + lane * 8);
            a = __builtin_amdgcn_mfma_f32_16x16x32_bf16(ahi[kt], bh, a, 0, 0, 0);
            a = __builtin_amdgcn_mfma_f32_16x16x32_bf16(alo[kt], bh, a, 0, 0, 0);
            a = __builtin_amdgcn_mfma_f32_16x16x32_bf16(ahi[kt], bl, a, 0, 0, 0);
        }
        acc[nt] = a;
    }

#pragma unroll
    for (int nt = 0; nt < 4; ++nt) {
#pragma unroll
        for (int r = 0; r < 4; ++r) {
            const uint32 d = (uint32)f2bf(acc[nt][r]) | ((uint32)f2bf(acc[nt + 4][r]) << 16);
            hbq[(size_t)(row0 + q * 4 + r) * 64 + nt * 16 + c15] = d;
        }
    }

    float aLacc[4][4] = {{0.f}}, aRacc[4][4] = {{0.f}};
#pragma unroll
    for (int nt = 0; nt < 8; ++nt) {
        const float alv = attl[nt * 16 + c15];
        const float arv = attr[nt * 16 + c15];
        const int hh = nt >> 1;
#pragma unroll
        for (int r = 0; r < 4; ++r) {
            aLacc[r][hh] = fmaf(acc[nt][r], alv, aLacc[r][hh]);
            aRacc[r][hh] = fmaf(acc[nt][r], arv, aRacc[r][hh]);
        }
    }
#pragma unroll
    for (int r = 0; r < 4; ++r) {
#pragma unroll
        for (int hh = 0; hh < 4; ++hh) {
            float vl = aLacc[r][hh], vr = aRacc[r][hh];
#pragma unroll
            for (int d = 1; d < 16; d <<= 1) {
                vl += __shfl_xor(vl, d);
                vr += __shfl_xor(vr, d);
            }
            if (c15 == hh) {
                const int row = row0 + q * 4 + r;
                const int pos = (hh & 1) * 2 + (hh >> 1);   // permuted slot
                aLp[row * N_HEADS + pos] = vl;
                aRp[row * N_HEADS + pos] = vr;
            }
        }
    }
}

// ---------------------------------------------------------------------------
// k_build: one block per bucket (391 blocks, 128 nodes each). Fixed CSR
// region rec_from[b*REC_CAP ...]. Reads its coalesced directory row
// (cnts/offs[b][0..511]), block-scans 512 run lengths, gathers the 512 dense
// runs from blockarr (4-MB L2/L3-hot footprint) into LDS stage; LDS
// histogram + scan -> count/offsets; scatter confined to own region.
// ---------------------------------------------------------------------------
__global__ __launch_bounds__(256) void k_build(const uint32* __restrict__ blockarr,
    const int* __restrict__ cnts, const int* __restrict__ offs,
    int* __restrict__ count, int* __restrict__ offsets, int* __restrict__ rec_from)
{
    __shared__ uint32 stage[STAGE_CAP];           // 10 KB
    __shared__ int hist[NPB], curn[NPB];
    const int b = blockIdx.x, t = threadIdx.x;

    int c[2], o[2];
#pragma unroll
    for (int j = 0; j < 2; ++j) {                 // coalesced directory row
        c[j] = cnts[(size_t)b * KA_GRID + 2 * t + j];
        o[j] = offs[(size_t)b * KA_GRID + 2 * t + j];
    }
    int total;
    int ex = block_scan_excl_256(c[0] + c[1], &total);
    if (t < NPB) hist[t] = 0;
    __syncthreads();

#pragma unroll
    for (int j = 0; j < 2; ++j) {                 // gather dense runs
        const int sb = 2 * t + j;
        const uint32* src = blockarr + (size_t)sb * EPB_PAD + o[j];
        for (int i = 0; i < c[j]; ++i) {
            const int p = ex + i;
            if (p < STAGE_CAP) stage[p] = src[i];
        }
        ex += c[j];
    }
    __syncthreads();

    const int S = min(total, STAGE_CAP);
    for (int i = t; i < S; i += 256) atomicAdd(&hist[stage[i] >> 16], 1);
    __syncthreads();

    const int hv = (t < NPB) ? hist[t] : 0;
    int tot2;
    const int lo = block_scan_excl_256(hv, &tot2);
    const int rbase = b * REC_CAP;
    const int n = b * NPB + t;
    if (t < NPB && n < N_NODES) {
        count[n]   = hv;
        offsets[n] = rbase + lo;
    }
    if (t < NPB) curn[t] = lo;
    __syncthreads();

    for (int i = t; i < S; i += 256) {
        const uint32 e = stage[i];
        const int pos = atomicAdd(&curn[e >> 16], 1);
        rec_from[rbase + pos] = (int)(e & 0xFFFFu);
    }
}

// ---------------------------------------------------------------------------
// k_agg (R13 verbatim): pull aggregation. Wave per node; lane l owns dims
// (l, l+64) via hbq word l — heads = permuted alpha slots (hsel, hsel+1).
// Half-wave exp dedup via shfl; unroll-by-8 for gather MLP.
// Softmax max-shift cancels in ex/sum(ex); att <= ~10 so no fp32 overflow.
// ---------------------------------------------------------------------------
__global__ __launch_bounds__(256) void k_agg(const int* __restrict__ rec_from,
    const int* __restrict__ count, const int* __restrict__ offsets,
    const float* __restrict__ aLp, const float* __restrict__ aRp,
    const uint32* __restrict__ hbq,
    const float* __restrict__ bias, float* __restrict__ out)
{
    const int lane = threadIdx.x & 63;
    const int n = blockIdx.x * 4 + (threadIdx.x >> 6);
    if (n >= N_NODES) return;
    const int cnt  = count[n];
    const int off  = offsets[n];
    const int hsel = (lane >> 5) * 2;   // permuted slot pair for this half-wave
    const int l31  = lane & 31;
    const int gsel = lane & 32;
    const float2 arv = *(const float2*)&aRp[n * N_HEADS + hsel];
    float ax = 0.f, ay = 0.f, ds0 = 0.f, ds1 = 0.f;

    for (int base = 0; base < cnt; base += 32) {
        const int m = min(32, cnt - base);
        int vf = 0;
        float e0p = 0.f, e1p = 0.f;
        if (l31 < m) {
            vf = rec_from[off + base + l31];                  // coalesced
            const float2 af = *(const float2*)&aLp[vf * N_HEADS + hsel];
            float t0 = af.x + arv.x; t0 = (t0 > 0.f) ? t0 : 0.2f * t0;
            float t1 = af.y + arv.y; t1 = (t1 > 0.f) ? t1 : 0.2f * t1;
            e0p = __expf(t0);
            e1p = __expf(t1);
        }
        int i = 0;
        for (; i + 8 <= m; i += 8) {
            int f[8]; uint32 h[8]; float e0[8], e1[8];
#pragma unroll
            for (int j = 0; j < 8; ++j) {
                const int s = gsel | (i + j);
                f[j]  = __shfl(vf, s);
                e0[j] = __shfl(e0p, s);
                e1[j] = __shfl(e1p, s);
            }
#pragma unroll
            for (int j = 0; j < 8; ++j) h[j] = hbq[(size_t)f[j] * 64 + lane];
#pragma unroll
            for (int j = 0; j < 8; ++j) {
                ax = fmaf(e0[j], __uint_as_float(h[j] << 16), ax);
                ay = fmaf(e1[j], __uint_as_float(h[j] & 0xFFFF0000u), ay);
                ds0 += e0[j]; ds1 += e1[j];
            }
        }
        for (; i + 4 <= m; i += 4) {
            int f[4]; uint32 h[4]; float e0[4], e1[4];
#pragma unroll
            for (int j = 0; j < 4; ++j) {
                const int s = gsel | (i + j);
                f[j]  = __shfl(vf, s);
                e0[j] = __shfl(e0p, s);
                e1[j] = __shfl(e1p, s);
            }
#pragma unroll
            for (int j = 0; j < 4; ++j) h[j] = hbq[(size_t)f[j] * 64 + lane];
#pragma unroll
            for (int j = 0; j < 4; ++j) {
                ax = fmaf(e0[j], __uint_as_float(h[j] << 16), ax);
                ay = fmaf(e1[j], __uint_as_float(h[j] & 0xFFFF0000u), ay);
                ds0 += e0[j]; ds1 += e1[j];
            }
        }
        for (; i < m; ++i) {
            const int s = gsel | i;
            const int f = __shfl(vf, s);
            const uint32 hv = hbq[(size_t)f * 64 + lane];
            const float e0 = __shfl(e0p, s), e1 = __shfl(e1p, s);
            ax = fmaf(e0, __uint_as_float(hv << 16), ax);
            ay = fmaf(e1, __uint_as_float(hv & 0xFFFF0000u), ay);
            ds0 += e0; ds1 += e1;
        }
    }
    const float inv0 = 1.0f / (ds0 + 1e-9f);
    const float inv1 = 1.0f / (ds1 + 1e-9f);
    out[n * F_OUT + lane]      = ax * inv0 + bias[lane];
    out[n * F_OUT + 64 + lane] = ay * inv1 + bias[64 + lane];
}

// ---------------------------------------------------------------------------
extern "C" void kernel_launch(void* const* d_in, const int* in_sizes, int n_in,
                              void* d_out, int out_size, void* d_ws, size_t ws_size,
                              hipStream_t stream)
{
    const float* x    = (const float*)d_in[0];
    const int*   ei   = (const int*)d_in[1];
    const float* W    = (const float*)d_in[2];
    const float* attl = (const float*)d_in[3];
    const float* attr = (const float*)d_in[4];
    const float* bias = (const float*)d_in[5];
    float* out = (float*)d_out;

    char* p = (char*)d_ws;
    auto carve = [&](size_t bytes) -> char* {
        char* q = p;
        p += (bytes + 255) & ~size_t(255);
        return q;
    };
    // total ~23.7 MB
    uint32* hbq      = (uint32*)carve((size_t)N_NODES * 64 * 4);           // 12.8 MB
    uint32* blockarr = (uint32*)carve((size_t)KA_GRID * EPB_PAD * 4);      // 3.2 MB
    int*    rec_from = (int*)carve((size_t)NBUCK * REC_CAP * 4);           // 4.0 MB
    ushort* WTF      = (ushort*)carve(32768 * 2);                          // 64 KB
    float*  aLp      = (float*)carve((size_t)N_NODES * N_HEADS * 4);
    float*  aRp      = (float*)carve((size_t)N_NODES * N_HEADS * 4);
    int*    cnts     = (int*)carve((size_t)NBUCK * KA_GRID * 4);           // 0.8 MB
    int*    offs     = (int*)carve((size_t)NBUCK * KA_GRID * 4);           // 0.8 MB
    int*    count    = (int*)carve((size_t)N_NODES * 4);
    int*    offsets  = (int*)carve((size_t)N_NODES * 4);

    k_prep<<<8, 256, 0, stream>>>(W, WTF);
    k_bin_gemm<<<KA_GRID + NGEMM, 256, 0, stream>>>(ei, x, WTF,
                                                    attl, attr, blockarr,
                                                    cnts, offs,
                                                    hbq, aLp, aRp);
    k_build<<<NBUCK, 256, 0, stream>>>(blockarr, cnts, offs,
                                       count, offsets, rec_from);
    k_agg<<<(N_NODES + 3) / 4, 256, 0, stream>>>(rec_from, count, offsets,
                                                 aLp, aRp, hbq, bias, out);
}